// Round 8
// baseline (443.827 us; speedup 1.0000x reference)
//
#include <hip/hip_runtime.h>

typedef float v4f __attribute__((ext_vector_type(4)));

namespace {
constexpr int B_     = 8;
constexpr int NT_    = 256;
constexpr int NX_    = 256;
constexpr int NREC_  = 64;
constexpr int PIECES = 16;             // vertical strips per batch
constexpr int IROWS  = 16;             // interior rows per strip
constexpr int G      = 16;             // ghost width = steps per round
constexpr int ROUNDS = NT_ / G;        // 16
constexpr int RPT    = 6;              // rows per thread (48 ext rows / 8 waves)
constexpr float DT2  = 1e-6f;          // DT*DT
constexpr float KLAP = 1e-8f;          // DT*DT/(DH*DH)
constexpr size_t FLAGS_BYTES = 4096;
constexpr int RCAP = 6;
} // namespace

// 128 blocks x 512 threads: piece p (0..15) of batch b, blockIdx = p*8 + b
// (neighbors p+-1 differ by 8 in blockIdx -> same XCD residue under round-robin
// dispatch; perf heuristic only, correctness rests on agent fences/flags).
// Each block evolves 48 ext rows (16 interior + 16 ghost each side) redundantly;
// cross-block exchange every G=16 steps (15 exchanges). Published slab = the
// whole interior (both levels) - serves BOTH neighbors, volume unchanged.
//
// R7 lesson: __shfl is ds_bpermute (LDS pipe!), so the reg-tile win was small;
// with 16 waves/CU the LDS pipe + barrier convoy floor is ~1.2us/step on 64
// CUs. R8: same total work on 128 CUs, 8-wave blocks -> per-CU LDS pressure
// and convoy halve. Thread tile 6x4 in registers (A,B,cf = 18 v4f ~100 VGPR;
// waves_per_eu(2,2) gives a 256-VGPR budget: structurally spill-proof).
extern "C" __global__
__attribute__((amdgpu_flat_work_group_size(512, 512), amdgpu_waves_per_eu(2, 2)))
void wave_reg16_kernel(const float* __restrict__ x,
                       const float* __restrict__ vp,
                       const int* __restrict__ src_loc,
                       const int* __restrict__ rec_loc,
                       float* __restrict__ out,
                       int* __restrict__ flags,   // [128] monotone round counters
                       float* __restrict__ gbuf)  // [par2][128][lvl2][16][256]
{
    __shared__ float pub[2][2][8][256];   // 16 KB: [par][top/bot][band][col]
    __shared__ float wav[NT_];            // 1 KB wavelet

    const int bid  = blockIdx.x;
    const int b    = bid & 7;
    const int p    = bid >> 3;             // piece 0..15
    const int blk  = b * PIECES + p;
    const int tid  = threadIdx.x;
    const int band = tid >> 6;             // wave id 0..7 -> 6 ext rows
    const int lane = tid & 63;
    const int c0   = lane << 2;            // first owned col (0..252)
    const int grt  = p * IROWS - G + band * RPT;   // global row of tile row 0

    if (tid < NT_) wav[tid] = x[b * NT_ + tid];

    // cf = vp^2*DT^2/DH^2, zeroed at Dirichlet boundary + out-of-domain rows
    v4f cf[RPT];
#pragma unroll
    for (int i = 0; i < RPT; ++i) {
        int gr = grt + i;
        int crow = gr < 0 ? 0 : (gr > 255 ? 255 : gr);
        bool rowok = (gr >= 1) && (gr <= 254);
        v4f vv = *(const v4f*)&vp[crow * NX_ + c0];
        float cc[4];
#pragma unroll
        for (int k = 0; k < 4; ++k) {
            int col = c0 + k;
            float vk = (k == 0) ? vv.x : (k == 1) ? vv.y : (k == 2) ? vv.z : vv.w;
            cc[k] = (rowok && col >= 1 && col <= 254) ? vk * vk * KLAP : 0.f;
        }
        cf[i].x = cc[0]; cf[i].y = cc[1]; cf[i].z = cc[2]; cf[i].w = cc[3];
    }

    // source ownership (ghost rows included: ghost evolution must replay it)
    const int sz = src_loc[b * 2 + 0], sx = src_loc[b * 2 + 1];
    const int si = sz - grt;               // 0..5 if owned row
    const int sj = sx - c0;                // 0..3 if owned col
    const bool has_src = ((unsigned)si < (unsigned)RPT) && ((unsigned)sj < 4u);

    // receiver slots: interior owner only (unique writer). pk=(r<<5)|(i<<2)|j
    int rs[RCAP]; int rcnt = 0;
#pragma unroll 1
    for (int r = 0; r < NREC_; ++r) {
        int rz = rec_loc[(b * NREC_ + r) * 2 + 0];
        int rx = rec_loc[(b * NREC_ + r) * 2 + 1];
        int i = rz - grt, j = rx - c0;
        if (rz >= p * IROWS && rz < p * IROWS + IROWS &&
            (unsigned)i < (unsigned)RPT && (unsigned)j < 4u) {
            if (rcnt < RCAP) rs[rcnt] = (r << 5) | (i << 2) | j;
            ++rcnt;
        }
    }
    if (rcnt > RCAP) rcnt = RCAP;
    float* outb = out + (size_t)b * NT_ * NREC_;

    v4f A[RPT], B[RPT];
    {
        v4f z = {0.f, 0.f, 0.f, 0.f};
#pragma unroll
        for (int i = 0; i < RPT; ++i) { A[i] = z; B[i] = z; }
    }

    // one step: P <- update(C, P); P becomes current. par = t&1.
    auto step = [&](v4f (&C)[RPT], v4f (&P)[RPT], int t, int par) {
        *(v4f*)&pub[par][0][band][c0] = C[0];       // top row -> band-1's south
        *(v4f*)&pub[par][1][band][c0] = C[RPT - 1]; // bottom row -> band+1's north
        __syncthreads();
        v4f nn, ss;
        if (band > 0) nn = *(const v4f*)&pub[par][1][band - 1][c0];
        else          { nn.x = 0.f; nn.y = 0.f; nn.z = 0.f; nn.w = 0.f; }
        if (band < 7) ss = *(const v4f*)&pub[par][0][band + 1][c0];
        else          { ss.x = 0.f; ss.y = 0.f; ss.z = 0.f; ss.w = 0.f; }
        const float sv = DT2 * wav[t];
#pragma unroll
        for (int i = 0; i < RPT; ++i) {
            v4f n = (i == 0)       ? nn : C[i - 1];
            v4f s = (i == RPT - 1) ? ss : C[i + 1];
            float wv = __shfl_up(C[i].w, 1, 64);   // col c0-1 (lane0 garbage: cf=0)
            float ev = __shfl_down(C[i].x, 1, 64); // col c0+4 (lane63 garbage: cf=0)
            v4f hn;
            { float sm = (n.x + s.x) + (wv     + C[i].y);
              hn.x = fmaf(cf[i].x, fmaf(-4.f, C[i].x, sm), fmaf(2.f, C[i].x, -P[i].x)); }
            { float sm = (n.y + s.y) + (C[i].x + C[i].z);
              hn.y = fmaf(cf[i].y, fmaf(-4.f, C[i].y, sm), fmaf(2.f, C[i].y, -P[i].y)); }
            { float sm = (n.z + s.z) + (C[i].y + C[i].w);
              hn.z = fmaf(cf[i].z, fmaf(-4.f, C[i].z, sm), fmaf(2.f, C[i].z, -P[i].z)); }
            { float sm = (n.w + s.w) + (C[i].z + ev);
              hn.w = fmaf(cf[i].w, fmaf(-4.f, C[i].w, sm), fmaf(2.f, C[i].w, -P[i].w)); }
            if (has_src && si == i) {
                if      (sj == 0) hn.x += sv;
                else if (sj == 1) hn.y += sv;
                else if (sj == 2) hn.z += sv;
                else              hn.w += sv;
            }
            P[i] = hn;
        }
        // receiver gather from the NEW level (registers)
#pragma unroll
        for (int k = 0; k < RCAP; ++k) {
            if (rcnt > k) {
                int pk = rs[k];
                int i = (pk >> 2) & 7, j = pk & 3, r = pk >> 5;
                v4f v01 = (i & 1) ? P[1] : P[0];
                v4f v23 = (i & 1) ? P[3] : P[2];
                v4f v45 = (i & 1) ? P[5] : P[4];
                v4f w03 = (i & 2) ? v23 : v01;
                v4f rw  = (i & 4) ? v45 : w03;
                float c01 = (j & 1) ? rw.y : rw.x;
                float c23 = (j & 1) ? rw.w : rw.z;
                outb[t * NREC_ + r] = (j & 2) ? c23 : c01;
            }
        }
        // no trailing barrier: next step uses pub[par^1] (parity double-buffer)
    };

    // ghost exchange after round e: publish my INTERIOR (ext rows 16..31, both
    // levels) once — serves both neighbors. R6/R7-proven fence/flag protocol.
    auto exchange = [&](int e) {
        auto gptr = [&](int bk, int lvl, int rr) -> float* {
            return gbuf + ((((size_t)(e & 1) * 128 + bk) * 2 + lvl) * 16 + rr) * 256;
        };
        {
            int er0 = band * RPT;          // publish rows with ext index in [16,32)
#pragma unroll
            for (int i = 0; i < RPT; ++i) {
                int er = er0 + i;
                if (er >= G && er < G + IROWS) {
                    int rr = er - G;
                    *(v4f*)&gptr(blk, 0, rr)[c0] = A[i];
                    *(v4f*)&gptr(blk, 1, rr)[c0] = B[i];
                }
            }
        }
        __syncthreads();                   // every wave's stores vmcnt-drained
        if (tid == 0) {
            __builtin_amdgcn_fence(__ATOMIC_RELEASE, "agent");
            __hip_atomic_store(&flags[blk], e + 1, __ATOMIC_RELEASE,
                               __HIP_MEMORY_SCOPE_AGENT);
            if (p > 0)
                while (__hip_atomic_load(&flags[blk - 1], __ATOMIC_ACQUIRE,
                                         __HIP_MEMORY_SCOPE_AGENT) < e + 1)
                    __builtin_amdgcn_s_sleep(8);
            __builtin_amdgcn_fence(__ATOMIC_ACQUIRE, "agent");
        }
        if (tid == 64 && p < PIECES - 1) { // wave 1 polls south in parallel
            while (__hip_atomic_load(&flags[blk + 1], __ATOMIC_ACQUIRE,
                                     __HIP_MEMORY_SCOPE_AGENT) < e + 1)
                __builtin_amdgcn_s_sleep(8);
            __builtin_amdgcn_fence(__ATOMIC_ACQUIRE, "agent");
        }
        __syncthreads();                   // all threads ordered after acquire
        {
            int er0 = band * RPT;
#pragma unroll
            for (int i = 0; i < RPT; ++i) {
                int er = er0 + i;
                if (er < G) {              // top ghost <- north neighbor interior
                    if (p > 0) {
                        A[i] = *(const v4f*)&gptr(blk - 1, 0, er)[c0];
                        B[i] = *(const v4f*)&gptr(blk - 1, 1, er)[c0];
                    }
                } else if (er >= G + IROWS) {  // bottom ghost <- south neighbor
                    if (p < PIECES - 1) {
                        int rr = er - (G + IROWS);
                        A[i] = *(const v4f*)&gptr(blk + 1, 0, rr)[c0];
                        B[i] = *(const v4f*)&gptr(blk + 1, 1, rr)[c0];
                    }
                }
            }
        }
    };

    int t = 0;
#pragma unroll 1
    for (int e = 0; e < ROUNDS; ++e) {
#pragma unroll 1
        for (int s = 0; s < G; s += 2) {
            step(A, B, t, 0);      // t even: cur=A, par=0
            step(B, A, t + 1, 1);  // t odd:  cur=B, par=1
            t += 2;
        }
        // after 16 steps: A = current level, B = previous level
        if (e < ROUNDS - 1) exchange(e);
    }
}

extern "C" void kernel_launch(void* const* d_in, const int* in_sizes, int n_in,
                              void* d_out, int out_size, void* d_ws, size_t ws_size,
                              hipStream_t stream) {
    const float* x   = (const float*)d_in[0];
    const float* vp  = (const float*)d_in[1];
    const int*   src = (const int*)d_in[2];
    const int*   rec = (const int*)d_in[3];
    float*       o   = (float*)d_out;
    int*   flags = (int*)d_ws;
    float* gbuf  = (float*)((char*)d_ws + FLAGS_BYTES);
    (void)hipMemsetAsync(d_ws, 0, FLAGS_BYTES, stream);   // flags must start at 0
    hipLaunchKernelGGL(wave_reg16_kernel, dim3(B_ * PIECES), dim3(512), 0, stream,
                       x, vp, src, rec, o, flags, gbuf);
}

// Round 10
// 407.932 us; speedup vs baseline: 1.0880x; 1.0880x over previous
//
#include <hip/hip_runtime.h>

typedef float v4f __attribute__((ext_vector_type(4)));

namespace {
constexpr int B_     = 8;
constexpr int NT_    = 256;
constexpr int NX_    = 256;
constexpr int NREC_  = 64;
constexpr int PIECES = 8;              // vertical strips per batch
constexpr int IROWS  = 32;             // interior rows per strip
constexpr int G      = 16;             // ghost width = steps per round
constexpr int ROUNDS = NT_ / G;        // 16
constexpr float DT2  = 1e-6f;          // DT*DT
constexpr float KLAP = 1e-8f;          // DT*DT/(DH*DH)
constexpr size_t FLAGS_BYTES = 4096;
constexpr int RCAP = 6;

// Whole-wave lane shifts via DPP (VALU op, no LDS pipe). Correct mapping
// (R9 erratum, verified against rocPRIM DPP scans): wave_shr:1 (0x138) =
// lane i <- lane i-1 (= shfl_up); wave_shl:1 (0x130) = lane i <- lane i+1
// (= shfl_down). bound_ctrl=true zeroes the edge lane - our cf=0 boundary
// columns make that value a don't-care.
__device__ __forceinline__ float dpp_up1(float v) {   // lane i <- lane i-1
    return __int_as_float(__builtin_amdgcn_update_dpp(
        0, __float_as_int(v), 0x138, 0xf, 0xf, true));   // wave_shr:1
}
__device__ __forceinline__ float dpp_dn1(float v) {   // lane i <- lane i+1
    return __int_as_float(__builtin_amdgcn_update_dpp(
        0, __float_as_int(v), 0x130, 0xf, 0xf, true));   // wave_shl:1
}
} // namespace

// 64 blocks: piece p of batch b (blockIdx = p*8 + b). Each block evolves 64 ext
// rows (32 interior + 16 ghost each side); cross-block exchange every G=16
// steps via cached slabs + agent-scope flag handshake (R6/R7-proven).
//
// R8 lesson: step cost ~1.2us is a latency tail (barrier + ds_read + bpermute
// chain), not throughput. R9/R10: kill the 8 per-step ds_bpermutes (horizontal
// halos) with DPP wave shifts; LDS ops/step drop 12 -> 4 and the dependent
// chain loses its longest hops. Config otherwise identical to R7 (the best).
extern "C" __global__
__attribute__((amdgpu_flat_work_group_size(1024, 1024), amdgpu_waves_per_eu(4, 4)))
void wave_dpp_kernel(const float* __restrict__ x,
                     const float* __restrict__ vp,
                     const int* __restrict__ src_loc,
                     const int* __restrict__ rec_loc,
                     float* __restrict__ out,
                     int* __restrict__ flags,   // [64] monotone round counters
                     float* __restrict__ gbuf)  // [par2][64][side2][lvl2][16][256]
{
    __shared__ float pub[2][2][16][256];  // 64 KB: [par][top/bot row][band][col]
    __shared__ float wav[NT_];            // 1 KB wavelet

    const int bid  = blockIdx.x;
    const int b    = bid & 7;
    const int p    = bid >> 3;
    const int blk  = b * PIECES + p;
    const int tid  = threadIdx.x;
    const int band = tid >> 6;             // wave id 0..15 -> 4 ext rows
    const int lane = tid & 63;
    const int c0   = lane << 2;            // first owned col (0..252)
    const int grt  = p * IROWS - G + (band << 2);  // global row of owned row 0

    if (tid < NT_) wav[tid] = x[b * NT_ + tid];

    // cf = vp^2*DT^2/DH^2, zeroed at Dirichlet boundary + out-of-domain rows
    v4f cf[4];
#pragma unroll
    for (int i = 0; i < 4; ++i) {
        int gr = grt + i;
        int crow = gr < 0 ? 0 : (gr > 255 ? 255 : gr);
        bool rowok = (gr >= 1) && (gr <= 254);
        v4f vv = *(const v4f*)&vp[crow * NX_ + c0];
        float cc[4];
#pragma unroll
        for (int k = 0; k < 4; ++k) {
            int col = c0 + k;
            float vk = (k == 0) ? vv.x : (k == 1) ? vv.y : (k == 2) ? vv.z : vv.w;
            cc[k] = (rowok && col >= 1 && col <= 254) ? vk * vk * KLAP : 0.f;
        }
        cf[i].x = cc[0]; cf[i].y = cc[1]; cf[i].z = cc[2]; cf[i].w = cc[3];
    }

    // source ownership (ghost rows included: ghost evolution must replay it)
    const int sz = src_loc[b * 2 + 0], sx = src_loc[b * 2 + 1];
    const int si = sz - grt;               // 0..3 if owned row
    const int sj = sx - c0;                // 0..3 if owned col
    const bool has_src = ((unsigned)si < 4u) && ((unsigned)sj < 4u);

    // receiver slots: interior owner only (unique writer). pk=(r<<4)|(i<<2)|j
    int rs[RCAP]; int rcnt = 0;
#pragma unroll 1
    for (int r = 0; r < NREC_; ++r) {
        int rz = rec_loc[(b * NREC_ + r) * 2 + 0];
        int rx = rec_loc[(b * NREC_ + r) * 2 + 1];
        int i = rz - grt, j = rx - c0;
        if (rz >= p * IROWS && rz < p * IROWS + IROWS &&
            (unsigned)i < 4u && (unsigned)j < 4u) {
            if (rcnt < RCAP) rs[rcnt] = (r << 4) | (i << 2) | j;
            ++rcnt;
        }
    }
    if (rcnt > RCAP) rcnt = RCAP;
    float* outb = out + (size_t)b * NT_ * NREC_;

    v4f A[4], B[4];
    {
        v4f z = {0.f, 0.f, 0.f, 0.f};
#pragma unroll
        for (int i = 0; i < 4; ++i) { A[i] = z; B[i] = z; }
    }

    // one step: P <- update(C, P); P becomes current. par = t&1.
    auto step = [&](v4f (&C)[4], v4f (&P)[4], int t, int par) {
        *(v4f*)&pub[par][0][band][c0] = C[0];   // my top row (south halo of band-1)
        *(v4f*)&pub[par][1][band][c0] = C[3];   // my bottom row (north halo of band+1)
        __syncthreads();
        v4f nn, ss;
        if (band > 0)  nn = *(const v4f*)&pub[par][1][band - 1][c0];
        else           { nn.x = 0.f; nn.y = 0.f; nn.z = 0.f; nn.w = 0.f; }
        if (band < 15) ss = *(const v4f*)&pub[par][0][band + 1][c0];
        else           { ss.x = 0.f; ss.y = 0.f; ss.z = 0.f; ss.w = 0.f; }
        const float sv = DT2 * wav[t];
#pragma unroll
        for (int i = 0; i < 4; ++i) {
            v4f n = (i == 0) ? nn : C[i - 1];
            v4f s = (i == 3) ? ss : C[i + 1];
            float wv = dpp_up1(C[i].w);   // col c0-1 (lane0 -> 0: col0 has cf=0)
            float ev = dpp_dn1(C[i].x);   // col c0+4 (lane63 -> 0: col255 cf=0)
            v4f hn;
            { float sm = (n.x + s.x) + (wv     + C[i].y);
              hn.x = fmaf(cf[i].x, fmaf(-4.f, C[i].x, sm), fmaf(2.f, C[i].x, -P[i].x)); }
            { float sm = (n.y + s.y) + (C[i].x + C[i].z);
              hn.y = fmaf(cf[i].y, fmaf(-4.f, C[i].y, sm), fmaf(2.f, C[i].y, -P[i].y)); }
            { float sm = (n.z + s.z) + (C[i].y + C[i].w);
              hn.z = fmaf(cf[i].z, fmaf(-4.f, C[i].z, sm), fmaf(2.f, C[i].z, -P[i].z)); }
            { float sm = (n.w + s.w) + (C[i].z + ev);
              hn.w = fmaf(cf[i].w, fmaf(-4.f, C[i].w, sm), fmaf(2.f, C[i].w, -P[i].w)); }
            if (has_src && si == i) {
                if      (sj == 0) hn.x += sv;
                else if (sj == 1) hn.y += sv;
                else if (sj == 2) hn.z += sv;
                else              hn.w += sv;
            }
            P[i] = hn;
        }
        // receiver gather from the NEW level (registers)
#pragma unroll
        for (int k = 0; k < RCAP; ++k) {
            if (rcnt > k) {
                int pk = rs[k];
                int i = (pk >> 2) & 3, j = pk & 3, r = pk >> 4;
                v4f t01 = (i & 1) ? P[1] : P[0];
                v4f t23 = (i & 1) ? P[3] : P[2];
                v4f rw  = (i & 2) ? t23 : t01;
                float c01 = (j & 1) ? rw.y : rw.x;
                float c23 = (j & 1) ? rw.w : rw.z;
                outb[t * NREC_ + r] = (j & 2) ? c23 : c01;
            }
        }
        // no trailing barrier: next step uses pub[par^1] (parity double-buffer)
    };

    // ghost exchange after round e: A=cur(lvl0), B=prev(lvl1), regs <-> global
    auto exchange = [&](int e) {
        auto gptr = [&](int bk, int side, int lvl, int rr) -> float* {
            return gbuf + (((((size_t)(e & 1) * 64 + bk) * 2 + side) * 2 + lvl)
                           * 16 + rr) * 256;
        };
        if (band >= 4 && band < 12) {      // publish interior halves, both levels
            int side = (band >= 8) ? 1 : 0;
            int rr0 = (band << 2) - (side ? 32 : 16);
#pragma unroll
            for (int i = 0; i < 4; ++i) {
                *(v4f*)&gptr(blk, side, 0, rr0 + i)[c0] = A[i];
                *(v4f*)&gptr(blk, side, 1, rr0 + i)[c0] = B[i];
            }
        }
        __syncthreads();                   // every wave's stores vmcnt-drained
        if (tid == 0) {
            __builtin_amdgcn_fence(__ATOMIC_RELEASE, "agent");
            __hip_atomic_store(&flags[blk], e + 1, __ATOMIC_RELEASE,
                               __HIP_MEMORY_SCOPE_AGENT);
            if (p > 0)
                while (__hip_atomic_load(&flags[blk - 1], __ATOMIC_ACQUIRE,
                                         __HIP_MEMORY_SCOPE_AGENT) < e + 1)
                    __builtin_amdgcn_s_sleep(8);
            __builtin_amdgcn_fence(__ATOMIC_ACQUIRE, "agent");
        }
        if (tid == 64 && p < PIECES - 1) { // second wave polls south in parallel
            while (__hip_atomic_load(&flags[blk + 1], __ATOMIC_ACQUIRE,
                                     __HIP_MEMORY_SCOPE_AGENT) < e + 1)
                __builtin_amdgcn_s_sleep(8);
            __builtin_amdgcn_fence(__ATOMIC_ACQUIRE, "agent");
        }
        __syncthreads();                   // all threads ordered after acquire
        if (band < 4 && p > 0) {           // refill top ghost from north neighbor
            int rr0 = band << 2;
#pragma unroll
            for (int i = 0; i < 4; ++i) {
                A[i] = *(const v4f*)&gptr(blk - 1, 1, 0, rr0 + i)[c0];
                B[i] = *(const v4f*)&gptr(blk - 1, 1, 1, rr0 + i)[c0];
            }
        }
        if (band >= 12 && p < PIECES - 1) {  // refill bottom ghost from south
            int rr0 = (band << 2) - 48;
#pragma unroll
            for (int i = 0; i < 4; ++i) {
                A[i] = *(const v4f*)&gptr(blk + 1, 0, 0, rr0 + i)[c0];
                B[i] = *(const v4f*)&gptr(blk + 1, 0, 1, rr0 + i)[c0];
            }
        }
    };

    int t = 0;
#pragma unroll 1
    for (int e = 0; e < ROUNDS; ++e) {
#pragma unroll 1
        for (int s = 0; s < G; s += 2) {
            step(A, B, t, 0);      // t even: cur=A, par=0
            step(B, A, t + 1, 1);  // t odd:  cur=B, par=1
            t += 2;
        }
        // after 16 steps: A = current level, B = previous level
        if (e < ROUNDS - 1) exchange(e);
    }
}

extern "C" void kernel_launch(void* const* d_in, const int* in_sizes, int n_in,
                              void* d_out, int out_size, void* d_ws, size_t ws_size,
                              hipStream_t stream) {
    const float* x   = (const float*)d_in[0];
    const float* vp  = (const float*)d_in[1];
    const int*   src = (const int*)d_in[2];
    const int*   rec = (const int*)d_in[3];
    float*       o   = (float*)d_out;
    int*   flags = (int*)d_ws;
    float* gbuf  = (float*)((char*)d_ws + FLAGS_BYTES);
    (void)hipMemsetAsync(d_ws, 0, FLAGS_BYTES, stream);   // flags must start at 0
    hipLaunchKernelGGL(wave_dpp_kernel, dim3(B_ * PIECES), dim3(1024), 0, stream,
                       x, vp, src, rec, o, flags, gbuf);
}